// Round 1
// baseline (134.401 us; speedup 1.0000x reference)
//
#include <hip/hip_runtime.h>

// Problem constants (HyperPatchNoPadding):
//   x: [8, 64, 256, 256] f32, s: [8, 4096, 16, 16] f32, out: [8, 64, 256, 256] f32
//   Per patch (b,pi,pj): Y[o][p*16+q] = sum_c W[o][c] * X[c][p*16+q]
//   W[o][c] = s[b][o*64+c][pi][pj];  X[c][n] = x[b][c][pi*16+p][pj*16+q]
#define NB   8
#define CIN  64
#define COUT 64
#define HH   256
#define WW   256
#define FH   16
#define FW   16

typedef __bf16 bf16x8 __attribute__((ext_vector_type(8)));
typedef float  f32x4  __attribute__((ext_vector_type(4)));

__global__ __launch_bounds__(256) void hyperpatch_kernel(
    const float* __restrict__ x,
    const float* __restrict__ s,
    float* __restrict__ out)
{
    // A-fragments of W in LDS, fragment-linear: idx g = (mt*2+kk)*64 + lane,
    // each entry = 8 bf16 (16B) holding W[mt*16+(lane&15)][kk*32+(lane>>4)*8 + j]
    __shared__ bf16x8 afrag[512];  // 8 KiB

    const int bid  = blockIdx.x;          // 0..2047
    const int b    = bid >> 8;            // batch
    const int pi   = (bid >> 4) & 15;     // patch row
    const int pj   = bid & 15;            // patch col
    const int t    = threadIdx.x;         // 0..255
    const int lane = t & 63;
    const int wv   = t >> 6;              // wave 0..3

    // ---------------- stage W (bf16 A-fragments) into LDS ----------------
    // s element (o,c) for this patch: s[((b*4096 + o*64 + c)*16 + pi)*16 + pj]
    const float* sbase = s + ((size_t)b * 4096) * 256 + pi * 16 + pj;
    #pragma unroll
    for (int gi = 0; gi < 2; ++gi) {
        const int g  = t + gi * 256;      // 0..511
        const int mt = g >> 7;            // 0..3
        const int kk = (g >> 6) & 1;      // 0..1
        const int gl = g & 63;            // fragment lane
        const int o  = mt * 16 + (gl & 15);
        const int c0 = kk * 32 + (gl >> 4) * 8;
        bf16x8 tv;
        #pragma unroll
        for (int j = 0; j < 8; ++j) {
            float v = sbase[(size_t)(o * 64 + c0 + j) * 256];
            tv[j] = (__bf16)v;
        }
        afrag[g] = tv;                    // contiguous 16B/lane -> conflict-free
    }

    // ---------------- load B-fragments of X straight from global ----------------
    // wave wv owns p = wv*4 .. wv*4+3 (n-tiles), q = lane&15, c = kk*32+(lane>>4)*8+j
    const int q  = lane & 15;
    const int cb = (lane >> 4) * 8;
    const float* xbase = x + (((size_t)b * 64) * 256 + pi * 16) * 256 + pj * 16 + q;
    // element (c,p): xbase[c*65536 + p*256]
    bf16x8 bfrag[4][2];
    #pragma unroll
    for (int nt = 0; nt < 4; ++nt) {
        const int p = wv * 4 + nt;
        #pragma unroll
        for (int kk = 0; kk < 2; ++kk) {
            const int c = kk * 32 + cb;
            bf16x8 tv;
            #pragma unroll
            for (int j = 0; j < 8; ++j) {
                float v = xbase[(size_t)(c + j) * 65536 + (size_t)p * 256];
                tv[j] = (__bf16)v;
            }
            bfrag[nt][kk] = tv;
        }
    }

    __syncthreads();

    // ---------------- read A-fragments from LDS ----------------
    bf16x8 a[4][2];
    #pragma unroll
    for (int mt = 0; mt < 4; ++mt)
        #pragma unroll
        for (int kk = 0; kk < 2; ++kk)
            a[mt][kk] = afrag[(mt * 2 + kk) * 64 + lane];

    // ---------------- MFMA: acc[mt][nt] = sum_kk A[mt][kk] * B[nt][kk] ----------------
    f32x4 acc[4][4];
    #pragma unroll
    for (int mt = 0; mt < 4; ++mt)
        #pragma unroll
        for (int nt = 0; nt < 4; ++nt)
            acc[mt][nt] = (f32x4){0.f, 0.f, 0.f, 0.f};

    #pragma unroll
    for (int mt = 0; mt < 4; ++mt) {
        #pragma unroll
        for (int nt = 0; nt < 4; ++nt) {
            acc[mt][nt] = __builtin_amdgcn_mfma_f32_16x16x32_bf16(
                a[mt][0], bfrag[nt][0], acc[mt][nt], 0, 0, 0);
            acc[mt][nt] = __builtin_amdgcn_mfma_f32_16x16x32_bf16(
                a[mt][1], bfrag[nt][1], acc[mt][nt], 0, 0, 0);
        }
    }

    // ---------------- store: out[b][o][pi*16+p][pj*16+q] ----------------
    // o = mt*16 + (lane>>4)*4 + r, p = wv*4+nt, q = lane&15
    const int ro = (lane >> 4) * 4;
    float* obase = out + (((size_t)b * 64) * 256 + pi * 16) * 256 + pj * 16 + q;
    #pragma unroll
    for (int mt = 0; mt < 4; ++mt) {
        #pragma unroll
        for (int nt = 0; nt < 4; ++nt) {
            const int p = wv * 4 + nt;
            #pragma unroll
            for (int r = 0; r < 4; ++r) {
                const int o = mt * 16 + ro + r;
                obase[(size_t)o * 65536 + (size_t)p * 256] = acc[mt][nt][r];
            }
        }
    }
}

extern "C" void kernel_launch(void* const* d_in, const int* in_sizes, int n_in,
                              void* d_out, int out_size, void* d_ws, size_t ws_size,
                              hipStream_t stream)
{
    (void)in_sizes; (void)n_in; (void)d_ws; (void)ws_size; (void)out_size;
    const float* x = (const float*)d_in[0];
    const float* s = (const float*)d_in[1];
    float* out = (float*)d_out;

    hyperpatch_kernel<<<dim3(NB * FH * FW), dim3(256), 0, stream>>>(x, s, out);
}

// Round 2
// 116.254 us; speedup vs baseline: 1.1561x; 1.1561x over previous
//
#include <hip/hip_runtime.h>

// HyperPatchNoPadding:
//   x: [8, 64, 256, 256] f32, s: [8, 4096, 16, 16] f32, out: [8, 64, 256, 256] f32
//   Per patch (b,pi,pj): Y[o][p*16+q] = sum_c W[o][c] * X[c][p*16+q]
//   W[o][c] = s[b][o*64+c][pi][pj];  X[c][n] = x[b][c][pi*16+p][pj*16+q]
// Round 2: one block = pj-PAIR of patches (full 128B x-line utilization),
//          512 threads = 8 waves (4 per patch), s gathered as float2.
#define NB   8
#define FH   16
#define FW   16

typedef __bf16 bf16x8 __attribute__((ext_vector_type(8)));
typedef float  f32x4  __attribute__((ext_vector_type(4)));

__global__ __launch_bounds__(512) void hyperpatch_kernel(
    const float* __restrict__ x,
    const float* __restrict__ s,
    float* __restrict__ out)
{
    // A-fragments of W in LDS for both patches of the pair, fragment-linear:
    // afrag[pat][(mt*2+kk)*64 + lane] = 8 bf16 of W[mt*16+(lane&15)][kk*32+(lane>>4)*8+j]
    __shared__ bf16x8 afrag[2][512];  // 16 KiB

    const int bid = blockIdx.x;           // 0..1023
    const int b   = bid >> 7;             // batch
    const int pi  = (bid >> 3) & 15;      // patch row
    const int pj0 = (bid & 7) * 2;        // left patch of the pair
    const int t   = threadIdx.x;          // 0..511
    const int lane = t & 63;
    const int wv   = t >> 6;              // wave 0..7

    // ---------------- stage W for BOTH patches (float2 gather) ----------------
    {
        const int g  = t;                 // 0..511 fragment entries
        const int mt = g >> 7;            // 0..3
        const int kk = (g >> 6) & 1;      // 0..1
        const int gl = g & 63;
        const int o  = mt * 16 + (gl & 15);
        const int c0 = kk * 32 + (gl >> 4) * 8;
        // s float-offset of (o,c) at (pi,pj0): ((b*4096+o*64+c)*16+pi)*16+pj0, pj0 even
        const float2* sb2 = reinterpret_cast<const float2*>(
            s + ((size_t)b * 4096) * 256 + pi * 16 + pj0);
        bf16x8 ta, tb;
        #pragma unroll
        for (int j = 0; j < 8; ++j) {
            float2 v = sb2[(size_t)(o * 64 + c0 + j) * 128];
            ta[j] = (__bf16)v.x;          // pj0   (patch 0)
            tb[j] = (__bf16)v.y;          // pj0+1 (patch 1)
        }
        afrag[0][g] = ta;
        afrag[1][g] = tb;
    }

    // ---------------- load B-fragments of X straight from global ----------------
    // wave wv: pat = wv>>2 selects patch, wrow = wv&3 selects p-rows (p = wrow*4+nt)
    const int pat  = wv >> 2;
    const int wrow = wv & 3;
    const int q  = lane & 15;
    const int cb = (lane >> 4) * 8;
    const float* xbase = x + (((size_t)b * 64) * 256 + pi * 16) * 256
                           + (pj0 + pat) * 16 + q;
    // element (c,p): xbase[c*65536 + p*256]
    bf16x8 bfrag[4][2];
    #pragma unroll
    for (int nt = 0; nt < 4; ++nt) {
        const int p = wrow * 4 + nt;
        #pragma unroll
        for (int kk = 0; kk < 2; ++kk) {
            const int c = kk * 32 + cb;
            bf16x8 tv;
            #pragma unroll
            for (int j = 0; j < 8; ++j) {
                float v = xbase[(size_t)(c + j) * 65536 + (size_t)p * 256];
                tv[j] = (__bf16)v;
            }
            bfrag[nt][kk] = tv;
        }
    }

    __syncthreads();

    // ---------------- read A-fragments from LDS ----------------
    bf16x8 a[4][2];
    #pragma unroll
    for (int mt = 0; mt < 4; ++mt)
        #pragma unroll
        for (int kk = 0; kk < 2; ++kk)
            a[mt][kk] = afrag[pat][(mt * 2 + kk) * 64 + lane];

    // ---------------- MFMA ----------------
    f32x4 acc[4][4];
    #pragma unroll
    for (int mt = 0; mt < 4; ++mt)
        #pragma unroll
        for (int nt = 0; nt < 4; ++nt)
            acc[mt][nt] = (f32x4){0.f, 0.f, 0.f, 0.f};

    #pragma unroll
    for (int mt = 0; mt < 4; ++mt) {
        #pragma unroll
        for (int nt = 0; nt < 4; ++nt) {
            acc[mt][nt] = __builtin_amdgcn_mfma_f32_16x16x32_bf16(
                a[mt][0], bfrag[nt][0], acc[mt][nt], 0, 0, 0);
            acc[mt][nt] = __builtin_amdgcn_mfma_f32_16x16x32_bf16(
                a[mt][1], bfrag[nt][1], acc[mt][nt], 0, 0, 0);
        }
    }

    // ---------------- store: out[b][o][pi*16+p][(pj0+pat)*16+q] ----------------
    // o = mt*16 + (lane>>4)*4 + r
    const int ro = (lane >> 4) * 4;
    float* obase = out + (((size_t)b * 64) * 256 + pi * 16) * 256
                       + (pj0 + pat) * 16 + q;
    #pragma unroll
    for (int mt = 0; mt < 4; ++mt) {
        #pragma unroll
        for (int nt = 0; nt < 4; ++nt) {
            const int p = wrow * 4 + nt;
            #pragma unroll
            for (int r = 0; r < 4; ++r) {
                const int o = mt * 16 + ro + r;
                obase[(size_t)o * 65536 + (size_t)p * 256] = acc[mt][nt][r];
            }
        }
    }
}

extern "C" void kernel_launch(void* const* d_in, const int* in_sizes, int n_in,
                              void* d_out, int out_size, void* d_ws, size_t ws_size,
                              hipStream_t stream)
{
    (void)in_sizes; (void)n_in; (void)d_ws; (void)ws_size; (void)out_size;
    const float* x = (const float*)d_in[0];
    const float* s = (const float*)d_in[1];
    float* out = (float*)d_out;

    hyperpatch_kernel<<<dim3(NB * FH * (FW / 2)), dim3(512), 0, stream>>>(x, s, out);
}

// Round 3
// 113.162 us; speedup vs baseline: 1.1877x; 1.0273x over previous
//
#include <hip/hip_runtime.h>

// HyperPatchNoPadding:
//   x: [8, 64, 256, 256] f32, s: [8, 4096, 16, 16] f32, out: [8, 64, 256, 256] f32
//   Per patch (b,pi,pj): Y[o][p*16+q] = sum_c W[o][c] * X[c][p*16+q]
//   W[o][c] = s[b][o*64+c][pi][pj];  X[c][n] = x[b][c][pi*16+p][pj*16+q]
//
// Round 3: two-kernel. K1 packs W into ws as bf16 MFMA A-fragments
// (coalesced read of s via LDS transpose); K2 is a gather-free GEMM with
// register-direct fragment loads (no LDS, no syncthreads).
#define NB 8
#define FH 16
#define FW 16

typedef __bf16 bf16x8 __attribute__((ext_vector_type(8)));
typedef float  f32x4  __attribute__((ext_vector_type(4)));

// ws layout: [patch = b*256 + pi*16 + pj][g = 0..511] entries of bf16x8 (16 B).
// entry g = (mt*2+kk)*64 + gl holds W[mt*16+(gl&15)][kk*32+(gl>>4)*8 + j], j=0..7.
#define WS_BYTES ((size_t)NB * 256 * 512 * 16)  // 16 MiB

// ---------------------------------------------------------------------------
// K1: pack/transpose s -> ws.  Block = (b, mt, kk, pi): 16 o x 32 c x 16 pj.
// Reads its 512 s-rows (64 B each) as float4 fully coalesced; LDS transpose;
// writes 16 patches' 1-KB fragment stripes with contiguous 16 B/lane stores.
// ---------------------------------------------------------------------------
__global__ __launch_bounds__(256) void pack_w_kernel(
    const float* __restrict__ s, bf16x8* __restrict__ ws)
{
    __shared__ float lds[16 * 513];          // [pj][cc*16 + row16], pad 1
    const int bid = blockIdx.x;              // 0..1023
    const int b   = bid >> 7;
    const int mt  = (bid >> 5) & 3;
    const int kk  = (bid >> 4) & 1;
    const int pi  = bid & 15;
    const int tid = threadIdx.x;             // 0..255

    #pragma unroll
    for (int pass = 0; pass < 8; ++pass) {
        const int idx   = pass * 256 + tid;  // 0..2047 = (u 0..511) x (pj4 0..3)
        const int u     = idx >> 2;
        const int pj4   = idx & 3;
        const int row16 = u >> 5;            // o - mt*16
        const int cc    = u & 31;            // c - kk*32
        const size_t row = (size_t)b * 4096 + mt * 1024 + row16 * 64 + kk * 32 + cc;
        const float4 v = *reinterpret_cast<const float4*>(
            s + row * 256 + pi * 16 + pj4 * 4);
        lds[(pj4 * 4 + 0) * 513 + cc * 16 + row16] = v.x;
        lds[(pj4 * 4 + 1) * 513 + cc * 16 + row16] = v.y;
        lds[(pj4 * 4 + 2) * 513 + cc * 16 + row16] = v.z;
        lds[(pj4 * 4 + 3) * 513 + cc * 16 + row16] = v.w;
    }
    __syncthreads();

    const int gl     = tid & 63;
    const int row16  = gl & 15;
    const int lanehi = gl >> 4;
    #pragma unroll
    for (int pjblk = 0; pjblk < 4; ++pjblk) {
        const int pj = pjblk * 4 + (tid >> 6);
        bf16x8 e;
        #pragma unroll
        for (int j = 0; j < 8; ++j)
            e[j] = (__bf16)lds[pj * 513 + (lanehi * 8 + j) * 16 + row16];
        ws[((size_t)(b * 256 + pi * 16 + pj)) * 512 + (mt * 2 + kk) * 64 + gl] = e;
    }
}

// ---------------------------------------------------------------------------
// K2: GEMM. Block = pj-pair (2 patches), 512 thr / 8 waves, no LDS, no sync.
// ---------------------------------------------------------------------------
__global__ __launch_bounds__(512) void gemm_kernel(
    const float* __restrict__ x,
    const bf16x8* __restrict__ ws,
    float* __restrict__ out)
{
    const int bid = blockIdx.x;           // 0..1023
    const int b   = bid >> 7;
    const int pi  = (bid >> 3) & 15;
    const int pj0 = (bid & 7) * 2;
    const int t   = threadIdx.x;
    const int lane = t & 63;
    const int wv   = t >> 6;              // 0..7
    const int pat  = wv >> 2;             // patch within pair
    const int wrow = wv & 3;              // p-row group

    // --- W fragments: register-direct, coalesced 16 B/lane ---
    const bf16x8* wbase = ws + ((size_t)(b * 256 + pi * 16 + pj0 + pat)) * 512;
    bf16x8 a[4][2];
    #pragma unroll
    for (int mt = 0; mt < 4; ++mt)
        #pragma unroll
        for (int kk = 0; kk < 2; ++kk)
            a[mt][kk] = wbase[(mt * 2 + kk) * 64 + lane];

    // --- X fragments straight from global ---
    const int q  = lane & 15;
    const int cb = (lane >> 4) * 8;
    const float* xbase = x + (((size_t)b * 64) * 256 + pi * 16) * 256
                           + (pj0 + pat) * 16 + q;
    bf16x8 bfrag[4][2];
    #pragma unroll
    for (int nt = 0; nt < 4; ++nt) {
        const int p = wrow * 4 + nt;
        #pragma unroll
        for (int kk = 0; kk < 2; ++kk) {
            const int c = kk * 32 + cb;
            bf16x8 tv;
            #pragma unroll
            for (int j = 0; j < 8; ++j) {
                float v = xbase[(size_t)(c + j) * 65536 + (size_t)p * 256];
                tv[j] = (__bf16)v;
            }
            bfrag[nt][kk] = tv;
        }
    }

    // --- MFMA ---
    f32x4 acc[4][4];
    #pragma unroll
    for (int mt = 0; mt < 4; ++mt)
        #pragma unroll
        for (int nt = 0; nt < 4; ++nt)
            acc[mt][nt] = (f32x4){0.f, 0.f, 0.f, 0.f};

    #pragma unroll
    for (int mt = 0; mt < 4; ++mt) {
        #pragma unroll
        for (int nt = 0; nt < 4; ++nt) {
            acc[mt][nt] = __builtin_amdgcn_mfma_f32_16x16x32_bf16(
                a[mt][0], bfrag[nt][0], acc[mt][nt], 0, 0, 0);
            acc[mt][nt] = __builtin_amdgcn_mfma_f32_16x16x32_bf16(
                a[mt][1], bfrag[nt][1], acc[mt][nt], 0, 0, 0);
        }
    }

    // --- store ---
    const int ro = (lane >> 4) * 4;
    float* obase = out + (((size_t)b * 64) * 256 + pi * 16) * 256
                       + (pj0 + pat) * 16 + q;
    #pragma unroll
    for (int mt = 0; mt < 4; ++mt) {
        #pragma unroll
        for (int nt = 0; nt < 4; ++nt) {
            const int p = wrow * 4 + nt;
            #pragma unroll
            for (int r = 0; r < 4; ++r) {
                const int o = mt * 16 + ro + r;
                obase[(size_t)o * 65536 + (size_t)p * 256] = acc[mt][nt][r];
            }
        }
    }
}

// ---------------------------------------------------------------------------
// Fallback (round-2 single kernel) if ws is too small.
// ---------------------------------------------------------------------------
__global__ __launch_bounds__(512) void hyperpatch_fallback(
    const float* __restrict__ x,
    const float* __restrict__ s,
    float* __restrict__ out)
{
    __shared__ bf16x8 afrag[2][512];
    const int bid = blockIdx.x;
    const int b   = bid >> 7;
    const int pi  = (bid >> 3) & 15;
    const int pj0 = (bid & 7) * 2;
    const int t   = threadIdx.x;
    const int lane = t & 63;
    const int wv   = t >> 6;

    {
        const int g  = t;
        const int mt = g >> 7;
        const int kk = (g >> 6) & 1;
        const int gl = g & 63;
        const int o  = mt * 16 + (gl & 15);
        const int c0 = kk * 32 + (gl >> 4) * 8;
        const float2* sb2 = reinterpret_cast<const float2*>(
            s + ((size_t)b * 4096) * 256 + pi * 16 + pj0);
        bf16x8 ta, tb;
        #pragma unroll
        for (int j = 0; j < 8; ++j) {
            float2 v = sb2[(size_t)(o * 64 + c0 + j) * 128];
            ta[j] = (__bf16)v.x;
            tb[j] = (__bf16)v.y;
        }
        afrag[0][g] = ta;
        afrag[1][g] = tb;
    }

    const int pat  = wv >> 2;
    const int wrow = wv & 3;
    const int q  = lane & 15;
    const int cb = (lane >> 4) * 8;
    const float* xbase = x + (((size_t)b * 64) * 256 + pi * 16) * 256
                           + (pj0 + pat) * 16 + q;
    bf16x8 bfrag[4][2];
    #pragma unroll
    for (int nt = 0; nt < 4; ++nt) {
        const int p = wrow * 4 + nt;
        #pragma unroll
        for (int kk = 0; kk < 2; ++kk) {
            const int c = kk * 32 + cb;
            bf16x8 tv;
            #pragma unroll
            for (int j = 0; j < 8; ++j) {
                float v = xbase[(size_t)(c + j) * 65536 + (size_t)p * 256];
                tv[j] = (__bf16)v;
            }
            bfrag[nt][kk] = tv;
        }
    }

    __syncthreads();

    bf16x8 a[4][2];
    #pragma unroll
    for (int mt = 0; mt < 4; ++mt)
        #pragma unroll
        for (int kk = 0; kk < 2; ++kk)
            a[mt][kk] = afrag[pat][(mt * 2 + kk) * 64 + lane];

    f32x4 acc[4][4];
    #pragma unroll
    for (int mt = 0; mt < 4; ++mt)
        #pragma unroll
        for (int nt = 0; nt < 4; ++nt)
            acc[mt][nt] = (f32x4){0.f, 0.f, 0.f, 0.f};

    #pragma unroll
    for (int mt = 0; mt < 4; ++mt) {
        #pragma unroll
        for (int nt = 0; nt < 4; ++nt) {
            acc[mt][nt] = __builtin_amdgcn_mfma_f32_16x16x32_bf16(
                a[mt][0], bfrag[nt][0], acc[mt][nt], 0, 0, 0);
            acc[mt][nt] = __builtin_amdgcn_mfma_f32_16x16x32_bf16(
                a[mt][1], bfrag[nt][1], acc[mt][nt], 0, 0, 0);
        }
    }

    const int ro = (lane >> 4) * 4;
    float* obase = out + (((size_t)b * 64) * 256 + pi * 16) * 256
                       + (pj0 + pat) * 16 + q;
    #pragma unroll
    for (int mt = 0; mt < 4; ++mt) {
        #pragma unroll
        for (int nt = 0; nt < 4; ++nt) {
            const int p = wrow * 4 + nt;
            #pragma unroll
            for (int r = 0; r < 4; ++r) {
                const int o = mt * 16 + ro + r;
                obase[(size_t)o * 65536 + (size_t)p * 256] = acc[mt][nt][r];
            }
        }
    }
}

extern "C" void kernel_launch(void* const* d_in, const int* in_sizes, int n_in,
                              void* d_out, int out_size, void* d_ws, size_t ws_size,
                              hipStream_t stream)
{
    (void)in_sizes; (void)n_in; (void)out_size;
    const float* x = (const float*)d_in[0];
    const float* s = (const float*)d_in[1];
    float* out = (float*)d_out;

    if (ws_size >= WS_BYTES && d_ws != nullptr) {
        bf16x8* ws = (bf16x8*)d_ws;
        pack_w_kernel<<<dim3(1024), dim3(256), 0, stream>>>(s, ws);
        gemm_kernel<<<dim3(1024), dim3(512), 0, stream>>>(x, ws, out);
    } else {
        hyperpatch_fallback<<<dim3(NB * FH * (FW / 2)), dim3(512), 0, stream>>>(x, s, out);
    }
}

// Round 5
// 77.990 us; speedup vs baseline: 1.7233x; 1.4510x over previous
//
#include <hip/hip_runtime.h>

// HyperPatchNoPadding:
//   x: [8, 64, 256, 256] f32, s: [8, 4096, 16, 16] f32, out: [8, 64, 256, 256] f32
//   Per patch (b,pi,pj): Y[o][p*16+q] = sum_c W[o][c] * X[c][p*16+q]
// Round 5: all-wide VMEM (128-B lines only). x transposed in-register
// (8c x 4w blocks) into XOR-swizzled LDS, B-fragments = single ds_read_b128.
// out staged through LDS -> f32x4 stores. W pre-packed (K1, proven).
#define NB 8
#define FH 16
#define FW 16

typedef __bf16 bf16x8 __attribute__((ext_vector_type(8)));
typedef float  f32x4  __attribute__((ext_vector_type(4)));

#define WS_BYTES ((size_t)NB * 256 * 512 * 16)  // 16 MiB

// ---------------------------------------------------------------------------
// K1: pack/transpose s -> ws (unchanged, proven in round 3).
// ws[patch][g]: g=(mt*2+kk)*64+gl holds W[mt*16+(gl&15)][kk*32+(gl>>4)*8+j]
// ---------------------------------------------------------------------------
__global__ __launch_bounds__(256) void pack_w_kernel(
    const float* __restrict__ s, bf16x8* __restrict__ ws)
{
    __shared__ float lds[16 * 513];
    const int bid = blockIdx.x;              // 0..1023
    const int b   = bid >> 7;
    const int mt  = (bid >> 5) & 3;
    const int kk  = (bid >> 4) & 1;
    const int pi  = bid & 15;
    const int tid = threadIdx.x;

    #pragma unroll
    for (int pass = 0; pass < 8; ++pass) {
        const int idx   = pass * 256 + tid;
        const int u     = idx >> 2;
        const int pj4   = idx & 3;
        const int row16 = u >> 5;
        const int cc    = u & 31;
        const size_t row = (size_t)b * 4096 + mt * 1024 + row16 * 64 + kk * 32 + cc;
        const float4 v = *reinterpret_cast<const float4*>(
            s + row * 256 + pi * 16 + pj4 * 4);
        lds[(pj4 * 4 + 0) * 513 + cc * 16 + row16] = v.x;
        lds[(pj4 * 4 + 1) * 513 + cc * 16 + row16] = v.y;
        lds[(pj4 * 4 + 2) * 513 + cc * 16 + row16] = v.z;
        lds[(pj4 * 4 + 3) * 513 + cc * 16 + row16] = v.w;
    }
    __syncthreads();

    const int gl     = tid & 63;
    const int row16  = gl & 15;
    const int lanehi = gl >> 4;
    #pragma unroll
    for (int pjblk = 0; pjblk < 4; ++pjblk) {
        const int pj = pjblk * 4 + (tid >> 6);
        bf16x8 e;
        #pragma unroll
        for (int j = 0; j < 8; ++j)
            e[j] = (__bf16)lds[pj * 513 + (lanehi * 8 + j) * 16 + row16];
        ws[((size_t)(b * 256 + pi * 16 + pj)) * 512 + (mt * 2 + kk) * 64 + gl] = e;
    }
}

// ---------------------------------------------------------------------------
// K2: GEMM. Block = pj-pair, 512 thr / 8 waves, 64 KiB LDS (dual-purpose).
// x-LDS layout: byte(p,w,c) = p*4096 + w*128 + ((c*2) ^ ((w&7)<<4) ^ ((p&7)<<4))
//   (XOR on 16-B slot bits only; every c-octet slot stays aligned+contiguous)
// ---------------------------------------------------------------------------
__global__ __launch_bounds__(512, 4) void gemm_kernel(
    const float* __restrict__ x,
    const bf16x8* __restrict__ ws,
    float* __restrict__ out)
{
    __shared__ char smem[65536];
    float* smemf = (float*)smem;

    const int bid = blockIdx.x;            // 0..1023
    const int b   = bid >> 7;
    const int pi  = (bid >> 3) & 15;
    const int pjp = bid & 7;
    const int t   = threadIdx.x;
    const int lane = t & 63;
    const int wv   = t >> 6;
    const int pat  = wv >> 2;
    const int wrow = wv & 3;
    const int q    = lane & 15;
    const int hi   = lane >> 4;
    const int w0   = pjp * 32;             // float offset of the pair in W-dim

    // ---- A fragments from ws (coalesced 16 B/lane, issued early) ----
    const bf16x8* wbase = ws + ((size_t)(b * 256 + pi * 16 + pjp * 2 + pat)) * 512;
    bf16x8 a[4][2];
    #pragma unroll
    for (int mt = 0; mt < 4; ++mt)
        #pragma unroll
        for (int kk = 0; kk < 2; ++kk)
            a[mt][kk] = wbase[(mt * 2 + kk) * 64 + lane];

    // ---- stage x -> LDS: lane owns (p = wv*2+pp, w-quad = lane&7, c-octet = lane>>3)
    {
        const int swq = lane & 7;          // w-quad 0..7 (w = swq*4+i)
        const int sco = lane >> 3;         // c-octet 0..7 (c = sco*8+cc)
        #pragma unroll
        for (int pp = 0; pp < 2; ++pp) {
            const int p = wv * 2 + pp;
            const float* xp = x + ((size_t)(b * 64 + sco * 8)) * 65536
                                + (size_t)(pi * 16 + p) * 256 + w0 + swq * 4;
            f32x4 v[8];
            #pragma unroll
            for (int cc = 0; cc < 8; ++cc)
                v[cc] = *(const f32x4*)(xp + (size_t)cc * 65536);  // full 128-B lines
            #pragma unroll
            for (int i = 0; i < 4; ++i) {
                const int w = swq * 4 + i;
                bf16x8 e;
                #pragma unroll
                for (int cc = 0; cc < 8; ++cc)
                    e[cc] = (__bf16)v[cc][i];
                *(bf16x8*)(smem + p * 4096 + w * 128
                           + ((sco * 16) ^ ((w & 7) << 4) ^ ((p & 7) << 4))) = e;
            }
        }
    }
    __syncthreads();

    // ---- B fragments: one ds_read_b128 each, c-contiguous in fragment order ----
    bf16x8 bfrag[4][2];
    #pragma unroll
    for (int nt = 0; nt < 4; ++nt) {
        const int p = wrow * 4 + nt;
        const int w = pat * 16 + q;
        #pragma unroll
        for (int kk = 0; kk < 2; ++kk) {
            const int co = kk * 4 + hi;    // c-octet = (kk*32+hi*8)/8
            bfrag[nt][kk] = *(const bf16x8*)(smem + p * 4096 + w * 128
                            + ((co * 16) ^ ((w & 7) << 4) ^ ((p & 7) << 4)));
        }
    }
    __syncthreads();                       // x-LDS now reusable for out-stage

    // ---- MFMA + out staging in two o-halves (o = h*32 + o2) ----
    const int u2t = t >> 3;                // 0..63
    const int wq2 = t & 7;
    const int p2  = u2t & 15;
    const int ol  = u2t >> 4;              // 0..3
    #pragma unroll
    for (int h = 0; h < 2; ++h) {
        f32x4 acc[2][4];
        #pragma unroll
        for (int m2 = 0; m2 < 2; ++m2)
            #pragma unroll
            for (int nt = 0; nt < 4; ++nt)
                acc[m2][nt] = (f32x4){0.f, 0.f, 0.f, 0.f};

        #pragma unroll
        for (int m2 = 0; m2 < 2; ++m2) {
            const int mt = h * 2 + m2;
            #pragma unroll
            for (int nt = 0; nt < 4; ++nt) {
                acc[m2][nt] = __builtin_amdgcn_mfma_f32_16x16x32_bf16(
                    a[mt][0], bfrag[nt][0], acc[m2][nt], 0, 0, 0);
                acc[m2][nt] = __builtin_amdgcn_mfma_f32_16x16x32_bf16(
                    a[mt][1], bfrag[nt][1], acc[m2][nt], 0, 0, 0);
            }
        }

        // acc -> LDS (swizzled: 2-way max on writes, balanced quads on reads)
        #pragma unroll
        for (int m2 = 0; m2 < 2; ++m2)
            #pragma unroll
            for (int nt = 0; nt < 4; ++nt) {
                const int p = wrow * 4 + nt;
                #pragma unroll
                for (int r = 0; r < 4; ++r) {
                    const int o2 = m2 * 16 + hi * 4 + r;
                    const int w  = pat * 16 + q;
                    smemf[(o2 * 16 + p) * 32 + (w ^ ((o2 & 7) << 2))] = acc[m2][nt][r];
                }
            }
        __syncthreads();

        // wide f32x4 stores: full 128-B lines
        #pragma unroll
        for (int ps = 0; ps < 8; ++ps) {
            const int o2 = ps * 4 + ol;
            f32x4 vv = *(const f32x4*)&smemf[(o2 * 16 + p2) * 32
                                             + ((wq2 * 4) ^ ((o2 & 7) << 2))];
            *(f32x4*)(out + ((size_t)(b * 64 + h * 32 + o2)) * 65536
                          + (size_t)(pi * 16 + p2) * 256 + w0 + wq2 * 4) = vv;
        }
        __syncthreads();
    }
}

// ---------------------------------------------------------------------------
// Fallback (round-2 single kernel, proven) if ws is too small.
// ---------------------------------------------------------------------------
__global__ __launch_bounds__(512) void hyperpatch_fallback(
    const float* __restrict__ x,
    const float* __restrict__ s,
    float* __restrict__ out)
{
    __shared__ bf16x8 afrag[2][512];
    const int bid = blockIdx.x;
    const int b   = bid >> 7;
    const int pi  = (bid >> 3) & 15;
    const int pj0 = (bid & 7) * 2;
    const int t   = threadIdx.x;
    const int lane = t & 63;
    const int wv   = t >> 6;

    {
        const int g  = t;
        const int mt = g >> 7;
        const int kk = (g >> 6) & 1;
        const int gl = g & 63;
        const int o  = mt * 16 + (gl & 15);
        const int c0 = kk * 32 + (gl >> 4) * 8;
        const float2* sb2 = reinterpret_cast<const float2*>(
            s + ((size_t)b * 4096) * 256 + pi * 16 + pj0);
        bf16x8 ta, tb;
        #pragma unroll
        for (int j = 0; j < 8; ++j) {
            float2 v = sb2[(size_t)(o * 64 + c0 + j) * 128];
            ta[j] = (__bf16)v.x;
            tb[j] = (__bf16)v.y;
        }
        afrag[0][g] = ta;
        afrag[1][g] = tb;
    }

    const int pat  = wv >> 2;
    const int wrow = wv & 3;
    const int q  = lane & 15;
    const int cb = (lane >> 4) * 8;
    const float* xbase = x + (((size_t)b * 64) * 256 + pi * 16) * 256
                           + (pj0 + pat) * 16 + q;
    bf16x8 bfrag[4][2];
    #pragma unroll
    for (int nt = 0; nt < 4; ++nt) {
        const int p = wrow * 4 + nt;
        #pragma unroll
        for (int kk = 0; kk < 2; ++kk) {
            const int c = kk * 32 + cb;
            bf16x8 tv;
            #pragma unroll
            for (int j = 0; j < 8; ++j) {
                float v = xbase[(size_t)(c + j) * 65536 + (size_t)p * 256];
                tv[j] = (__bf16)v;
            }
            bfrag[nt][kk] = tv;
        }
    }

    __syncthreads();

    bf16x8 a[4][2];
    #pragma unroll
    for (int mt = 0; mt < 4; ++mt)
        #pragma unroll
        for (int kk = 0; kk < 2; ++kk)
            a[mt][kk] = afrag[pat][(mt * 2 + kk) * 64 + lane];

    f32x4 acc[4][4];
    #pragma unroll
    for (int mt = 0; mt < 4; ++mt)
        #pragma unroll
        for (int nt = 0; nt < 4; ++nt)
            acc[mt][nt] = (f32x4){0.f, 0.f, 0.f, 0.f};

    #pragma unroll
    for (int mt = 0; mt < 4; ++mt) {
        #pragma unroll
        for (int nt = 0; nt < 4; ++nt) {
            acc[mt][nt] = __builtin_amdgcn_mfma_f32_16x16x32_bf16(
                a[mt][0], bfrag[nt][0], acc[mt][nt], 0, 0, 0);
            acc[mt][nt] = __builtin_amdgcn_mfma_f32_16x16x32_bf16(
                a[mt][1], bfrag[nt][1], acc[mt][nt], 0, 0, 0);
        }
    }

    const int ro = (lane >> 4) * 4;
    float* obase = out + (((size_t)b * 64) * 256 + pi * 16) * 256
                       + (pj0 + pat) * 16 + q;
    #pragma unroll
    for (int mt = 0; mt < 4; ++mt) {
        #pragma unroll
        for (int nt = 0; nt < 4; ++nt) {
            const int p = wrow * 4 + nt;
            #pragma unroll
            for (int r = 0; r < 4; ++r) {
                const int o = mt * 16 + ro + r;
                obase[(size_t)o * 65536 + (size_t)p * 256] = acc[mt][nt][r];
            }
        }
    }
}

extern "C" void kernel_launch(void* const* d_in, const int* in_sizes, int n_in,
                              void* d_out, int out_size, void* d_ws, size_t ws_size,
                              hipStream_t stream)
{
    (void)in_sizes; (void)n_in; (void)out_size;
    const float* x = (const float*)d_in[0];
    const float* s = (const float*)d_in[1];
    float* out = (float*)d_out;

    if (ws_size >= WS_BYTES && d_ws != nullptr) {
        bf16x8* ws = (bf16x8*)d_ws;
        pack_w_kernel<<<dim3(1024), dim3(256), 0, stream>>>(s, ws);
        gemm_kernel<<<dim3(1024), dim3(512), 0, stream>>>(x, ws, out);
    } else {
        hyperpatch_fallback<<<dim3(NB * FH * (FW / 2)), dim3(512), 0, stream>>>(x, s, out);
    }
}

// Round 6
// 75.336 us; speedup vs baseline: 1.7840x; 1.0352x over previous
//
#include <hip/hip_runtime.h>

// HyperPatchNoPadding:
//   x: [8, 64, 256, 256] f32, s: [8, 4096, 16, 16] f32, out: [8, 64, 256, 256] f32
//   Per patch (b,pi,pj): Y[o][p*16+q] = sum_c W[o][c] * X[c][p*16+q]
// Round 6: identical kernels to round 5; ONLY the block-index decode is
// permuted so XCD id (blockIdx%8) maps to b (high address bits) instead of
// pjp/pi (which set L2-channel bits 7-9). Fixes per-XCD L2 channel collapse.
#define NB 8
#define FH 16
#define FW 16

typedef __bf16 bf16x8 __attribute__((ext_vector_type(8)));
typedef float  f32x4  __attribute__((ext_vector_type(4)));

#define WS_BYTES ((size_t)NB * 256 * 512 * 16)  // 16 MiB

// ---------------------------------------------------------------------------
// K1: pack/transpose s -> ws.  ws[patch][g]: g=(mt*2+kk)*64+gl holds
// W[mt*16+(gl&15)][kk*32+(gl>>4)*8+j]
// ---------------------------------------------------------------------------
__global__ __launch_bounds__(256) void pack_w_kernel(
    const float* __restrict__ s, bf16x8* __restrict__ ws)
{
    __shared__ float lds[16 * 513];
    const int bid = blockIdx.x;              // 0..1023
    const int b   = bid & 7;                 // XCD-selecting bits -> b
    const int pi  = (bid >> 3) & 15;
    const int mt  = (bid >> 7) & 3;
    const int kk  = (bid >> 9) & 1;
    const int tid = threadIdx.x;

    #pragma unroll
    for (int pass = 0; pass < 8; ++pass) {
        const int idx   = pass * 256 + tid;
        const int u     = idx >> 2;
        const int pj4   = idx & 3;
        const int row16 = u >> 5;
        const int cc    = u & 31;
        const size_t row = (size_t)b * 4096 + mt * 1024 + row16 * 64 + kk * 32 + cc;
        const float4 v = *reinterpret_cast<const float4*>(
            s + row * 256 + pi * 16 + pj4 * 4);
        lds[(pj4 * 4 + 0) * 513 + cc * 16 + row16] = v.x;
        lds[(pj4 * 4 + 1) * 513 + cc * 16 + row16] = v.y;
        lds[(pj4 * 4 + 2) * 513 + cc * 16 + row16] = v.z;
        lds[(pj4 * 4 + 3) * 513 + cc * 16 + row16] = v.w;
    }
    __syncthreads();

    const int gl     = tid & 63;
    const int row16  = gl & 15;
    const int lanehi = gl >> 4;
    #pragma unroll
    for (int pjblk = 0; pjblk < 4; ++pjblk) {
        const int pj = pjblk * 4 + (tid >> 6);
        bf16x8 e;
        #pragma unroll
        for (int j = 0; j < 8; ++j)
            e[j] = (__bf16)lds[pj * 513 + (lanehi * 8 + j) * 16 + row16];
        ws[((size_t)(b * 256 + pi * 16 + pj)) * 512 + (mt * 2 + kk) * 64 + gl] = e;
    }
}

// ---------------------------------------------------------------------------
// K2: GEMM. Block = pj-pair, 512 thr / 8 waves, 64 KiB LDS (dual-purpose).
// x-LDS layout: byte(p,w,c) = p*4096 + w*128 + ((c*2) ^ ((w&7)<<4) ^ ((p&7)<<4))
// ---------------------------------------------------------------------------
__global__ __launch_bounds__(512, 4) void gemm_kernel(
    const float* __restrict__ x,
    const bf16x8* __restrict__ ws,
    float* __restrict__ out)
{
    __shared__ char smem[65536];
    float* smemf = (float*)smem;

    const int bid = blockIdx.x;            // 0..1023
    const int b   = bid & 7;               // XCD-selecting bits -> b
    const int pi  = (bid >> 3) & 15;
    const int pjp = bid >> 7;
    const int t   = threadIdx.x;
    const int lane = t & 63;
    const int wv   = t >> 6;
    const int pat  = wv >> 2;
    const int wrow = wv & 3;
    const int q    = lane & 15;
    const int hi   = lane >> 4;
    const int w0   = pjp * 32;             // float offset of the pair in W-dim

    // ---- A fragments from ws (coalesced 16 B/lane, issued early) ----
    const bf16x8* wbase = ws + ((size_t)(b * 256 + pi * 16 + pjp * 2 + pat)) * 512;
    bf16x8 a[4][2];
    #pragma unroll
    for (int mt = 0; mt < 4; ++mt)
        #pragma unroll
        for (int kk = 0; kk < 2; ++kk)
            a[mt][kk] = wbase[(mt * 2 + kk) * 64 + lane];

    // ---- stage x -> LDS: lane owns (p = wv*2+pp, w-quad = lane&7, c-octet = lane>>3)
    {
        const int swq = lane & 7;          // w-quad 0..7 (w = swq*4+i)
        const int sco = lane >> 3;         // c-octet 0..7 (c = sco*8+cc)
        #pragma unroll
        for (int pp = 0; pp < 2; ++pp) {
            const int p = wv * 2 + pp;
            const float* xp = x + ((size_t)(b * 64 + sco * 8)) * 65536
                                + (size_t)(pi * 16 + p) * 256 + w0 + swq * 4;
            f32x4 v[8];
            #pragma unroll
            for (int cc = 0; cc < 8; ++cc)
                v[cc] = *(const f32x4*)(xp + (size_t)cc * 65536);  // full 128-B lines
            #pragma unroll
            for (int i = 0; i < 4; ++i) {
                const int w = swq * 4 + i;
                bf16x8 e;
                #pragma unroll
                for (int cc = 0; cc < 8; ++cc)
                    e[cc] = (__bf16)v[cc][i];
                *(bf16x8*)(smem + p * 4096 + w * 128
                           + ((sco * 16) ^ ((w & 7) << 4) ^ ((p & 7) << 4))) = e;
            }
        }
    }
    __syncthreads();

    // ---- B fragments: one ds_read_b128 each, c-contiguous in fragment order ----
    bf16x8 bfrag[4][2];
    #pragma unroll
    for (int nt = 0; nt < 4; ++nt) {
        const int p = wrow * 4 + nt;
        const int w = pat * 16 + q;
        #pragma unroll
        for (int kk = 0; kk < 2; ++kk) {
            const int co = kk * 4 + hi;    // c-octet = (kk*32+hi*8)/8
            bfrag[nt][kk] = *(const bf16x8*)(smem + p * 4096 + w * 128
                            + ((co * 16) ^ ((w & 7) << 4) ^ ((p & 7) << 4)));
        }
    }
    __syncthreads();                       // x-LDS now reusable for out-stage

    // ---- MFMA + out staging in two o-halves (o = h*32 + o2) ----
    const int u2t = t >> 3;                // 0..63
    const int wq2 = t & 7;
    const int p2  = u2t & 15;
    const int ol  = u2t >> 4;              // 0..3
    #pragma unroll
    for (int h = 0; h < 2; ++h) {
        f32x4 acc[2][4];
        #pragma unroll
        for (int m2 = 0; m2 < 2; ++m2)
            #pragma unroll
            for (int nt = 0; nt < 4; ++nt)
                acc[m2][nt] = (f32x4){0.f, 0.f, 0.f, 0.f};

        #pragma unroll
        for (int m2 = 0; m2 < 2; ++m2) {
            const int mt = h * 2 + m2;
            #pragma unroll
            for (int nt = 0; nt < 4; ++nt) {
                acc[m2][nt] = __builtin_amdgcn_mfma_f32_16x16x32_bf16(
                    a[mt][0], bfrag[nt][0], acc[m2][nt], 0, 0, 0);
                acc[m2][nt] = __builtin_amdgcn_mfma_f32_16x16x32_bf16(
                    a[mt][1], bfrag[nt][1], acc[m2][nt], 0, 0, 0);
            }
        }

        // acc -> LDS (swizzled)
        #pragma unroll
        for (int m2 = 0; m2 < 2; ++m2)
            #pragma unroll
            for (int nt = 0; nt < 4; ++nt) {
                const int p = wrow * 4 + nt;
                #pragma unroll
                for (int r = 0; r < 4; ++r) {
                    const int o2 = m2 * 16 + hi * 4 + r;
                    const int w  = pat * 16 + q;
                    smemf[(o2 * 16 + p) * 32 + (w ^ ((o2 & 7) << 2))] = acc[m2][nt][r];
                }
            }
        __syncthreads();

        // wide f32x4 stores: full 128-B lines
        #pragma unroll
        for (int ps = 0; ps < 8; ++ps) {
            const int o2 = ps * 4 + ol;
            f32x4 vv = *(const f32x4*)&smemf[(o2 * 16 + p2) * 32
                                             + ((wq2 * 4) ^ ((o2 & 7) << 2))];
            *(f32x4*)(out + ((size_t)(b * 64 + h * 32 + o2)) * 65536
                          + (size_t)(pi * 16 + p2) * 256 + w0 + wq2 * 4) = vv;
        }
        __syncthreads();
    }
}

// ---------------------------------------------------------------------------
// Fallback (round-2 single kernel, proven) if ws is too small.
// ---------------------------------------------------------------------------
__global__ __launch_bounds__(512) void hyperpatch_fallback(
    const float* __restrict__ x,
    const float* __restrict__ s,
    float* __restrict__ out)
{
    __shared__ bf16x8 afrag[2][512];
    const int bid = blockIdx.x;
    const int b   = bid >> 7;
    const int pi  = (bid >> 3) & 15;
    const int pj0 = (bid & 7) * 2;
    const int t   = threadIdx.x;
    const int lane = t & 63;
    const int wv   = t >> 6;

    {
        const int g  = t;
        const int mt = g >> 7;
        const int kk = (g >> 6) & 1;
        const int gl = g & 63;
        const int o  = mt * 16 + (gl & 15);
        const int c0 = kk * 32 + (gl >> 4) * 8;
        const float2* sb2 = reinterpret_cast<const float2*>(
            s + ((size_t)b * 4096) * 256 + pi * 16 + pj0);
        bf16x8 ta, tb;
        #pragma unroll
        for (int j = 0; j < 8; ++j) {
            float2 v = sb2[(size_t)(o * 64 + c0 + j) * 128];
            ta[j] = (__bf16)v.x;
            tb[j] = (__bf16)v.y;
        }
        afrag[0][g] = ta;
        afrag[1][g] = tb;
    }

    const int pat  = wv >> 2;
    const int wrow = wv & 3;
    const int q  = lane & 15;
    const int cb = (lane >> 4) * 8;
    const float* xbase = x + (((size_t)b * 64) * 256 + pi * 16) * 256
                           + (pj0 + pat) * 16 + q;
    bf16x8 bfrag[4][2];
    #pragma unroll
    for (int nt = 0; nt < 4; ++nt) {
        const int p = wrow * 4 + nt;
        #pragma unroll
        for (int kk = 0; kk < 2; ++kk) {
            const int c = kk * 32 + cb;
            bf16x8 tv;
            #pragma unroll
            for (int j = 0; j < 8; ++j) {
                float v = xbase[(size_t)(c + j) * 65536 + (size_t)p * 256];
                tv[j] = (__bf16)v;
            }
            bfrag[nt][kk] = tv;
        }
    }

    __syncthreads();

    bf16x8 a[4][2];
    #pragma unroll
    for (int mt = 0; mt < 4; ++mt)
        #pragma unroll
        for (int kk = 0; kk < 2; ++kk)
            a[mt][kk] = afrag[pat][(mt * 2 + kk) * 64 + lane];

    f32x4 acc[4][4];
    #pragma unroll
    for (int mt = 0; mt < 4; ++mt)
        #pragma unroll
        for (int nt = 0; nt < 4; ++nt)
            acc[mt][nt] = (f32x4){0.f, 0.f, 0.f, 0.f};

    #pragma unroll
    for (int mt = 0; mt < 4; ++mt) {
        #pragma unroll
        for (int nt = 0; nt < 4; ++nt) {
            acc[mt][nt] = __builtin_amdgcn_mfma_f32_16x16x32_bf16(
                a[mt][0], bfrag[nt][0], acc[mt][nt], 0, 0, 0);
            acc[mt][nt] = __builtin_amdgcn_mfma_f32_16x16x32_bf16(
                a[mt][1], bfrag[nt][1], acc[mt][nt], 0, 0, 0);
        }
    }

    const int ro = (lane >> 4) * 4;
    float* obase = out + (((size_t)b * 64) * 256 + pi * 16) * 256
                       + (pj0 + pat) * 16 + q;
    #pragma unroll
    for (int mt = 0; mt < 4; ++mt) {
        #pragma unroll
        for (int nt = 0; nt < 4; ++nt) {
            const int p = wrow * 4 + nt;
            #pragma unroll
            for (int r = 0; r < 4; ++r) {
                const int o = mt * 16 + ro + r;
                obase[(size_t)o * 65536 + (size_t)p * 256] = acc[mt][nt][r];
            }
        }
    }
}

extern "C" void kernel_launch(void* const* d_in, const int* in_sizes, int n_in,
                              void* d_out, int out_size, void* d_ws, size_t ws_size,
                              hipStream_t stream)
{
    (void)in_sizes; (void)n_in; (void)out_size;
    const float* x = (const float*)d_in[0];
    const float* s = (const float*)d_in[1];
    float* out = (float*)d_out;

    if (ws_size >= WS_BYTES && d_ws != nullptr) {
        bf16x8* ws = (bf16x8*)d_ws;
        pack_w_kernel<<<dim3(1024), dim3(256), 0, stream>>>(s, ws);
        gemm_kernel<<<dim3(1024), dim3(512), 0, stream>>>(x, ws, out);
    } else {
        hyperpatch_fallback<<<dim3(NB * FH * (FW / 2)), dim3(512), 0, stream>>>(x, s, out);
    }
}

// Round 7
// 73.271 us; speedup vs baseline: 1.8343x; 1.0282x over previous
//
#include <hip/hip_runtime.h>

// HyperPatchNoPadding:
//   x: [8, 64, 256, 256] f32, s: [8, 4096, 16, 16] f32, out: [8, 64, 256, 256] f32
//   Per patch (b,pi,pj): Y[o][p*16+q] = sum_c W[o][c] * X[c][p*16+q]
// Round 7: same dataflow as round 5/6, rescaled for occupancy/overlap:
//   block = 256 thr (4 waves), 32 KiB LDS, handles (b, pi, p-half, pj-pair).
//   -> 5 blocks/CU by LDS (was 2), ~20 waves/CU, barriers decoupled.
#define NB 8
#define FH 16
#define FW 16

typedef __bf16 bf16x8 __attribute__((ext_vector_type(8)));
typedef float  f32x4  __attribute__((ext_vector_type(4)));

#define WS_BYTES ((size_t)NB * 256 * 512 * 16)  // 16 MiB

// ---------------------------------------------------------------------------
// K1: pack/transpose s -> ws (proven).  ws[patch][g]: g=(mt*2+kk)*64+gl holds
// W[mt*16+(gl&15)][kk*32+(gl>>4)*8+j]
// ---------------------------------------------------------------------------
__global__ __launch_bounds__(256) void pack_w_kernel(
    const float* __restrict__ s, bf16x8* __restrict__ ws)
{
    __shared__ float lds[16 * 513];
    const int bid = blockIdx.x;              // 0..1023
    const int b   = bid & 7;                 // XCD bits -> b
    const int pi  = (bid >> 3) & 15;
    const int mt  = (bid >> 7) & 3;
    const int kk  = (bid >> 9) & 1;
    const int tid = threadIdx.x;

    #pragma unroll
    for (int pass = 0; pass < 8; ++pass) {
        const int idx   = pass * 256 + tid;
        const int u     = idx >> 2;
        const int pj4   = idx & 3;
        const int row16 = u >> 5;
        const int cc    = u & 31;
        const size_t row = (size_t)b * 4096 + mt * 1024 + row16 * 64 + kk * 32 + cc;
        const float4 v = *reinterpret_cast<const float4*>(
            s + row * 256 + pi * 16 + pj4 * 4);
        lds[(pj4 * 4 + 0) * 513 + cc * 16 + row16] = v.x;
        lds[(pj4 * 4 + 1) * 513 + cc * 16 + row16] = v.y;
        lds[(pj4 * 4 + 2) * 513 + cc * 16 + row16] = v.z;
        lds[(pj4 * 4 + 3) * 513 + cc * 16 + row16] = v.w;
    }
    __syncthreads();

    const int gl     = tid & 63;
    const int row16  = gl & 15;
    const int lanehi = gl >> 4;
    #pragma unroll
    for (int pjblk = 0; pjblk < 4; ++pjblk) {
        const int pj = pjblk * 4 + (tid >> 6);
        bf16x8 e;
        #pragma unroll
        for (int j = 0; j < 8; ++j)
            e[j] = (__bf16)lds[pj * 513 + (lanehi * 8 + j) * 16 + row16];
        ws[((size_t)(b * 256 + pi * 16 + pj)) * 512 + (mt * 2 + kk) * 64 + gl] = e;
    }
}

// ---------------------------------------------------------------------------
// K2: GEMM. Block = (b, pi, ph, pjp): 8 p-rows x 2 patches. 256 thr / 4 waves,
// 32 KiB LDS dual-purpose.
// x-LDS: byte(p,w,c) = p*4096 + w*128 + ((c*2) ^ ((w&7)<<4) ^ ((p&7)<<4)), p<8
// ---------------------------------------------------------------------------
__global__ __launch_bounds__(256, 4) void gemm_kernel(
    const float* __restrict__ x,
    const bf16x8* __restrict__ ws,
    float* __restrict__ out)
{
    __shared__ char smem[32768];
    float* smemf = (float*)smem;

    const int bid = blockIdx.x;            // 0..2047
    const int b   = bid & 7;               // XCD bits -> b
    const int pi  = (bid >> 3) & 15;
    const int ph  = (bid >> 7) & 1;        // p half (rows pi*16+ph*8 ..+7)
    const int pjp = (bid >> 8) & 7;        // pj pair
    const int t   = threadIdx.x;           // 0..255
    const int lane = t & 63;
    const int wv   = t >> 6;               // 0..3
    const int pat  = wv & 1;               // patch within pair
    const int wrow = wv >> 1;              // p quad (p = wrow*4+nt)
    const int q    = lane & 15;
    const int hi   = lane >> 4;
    const int w0   = pjp * 32;             // float offset of pair in W-dim
    const int row0 = pi * 16 + ph * 8;     // global h-row base

    // ---- A fragments from ws (coalesced 16 B/lane) ----
    const bf16x8* wbase = ws + ((size_t)(b * 256 + pi * 16 + pjp * 2 + pat)) * 512;
    bf16x8 a[4][2];
    #pragma unroll
    for (int mt = 0; mt < 4; ++mt)
        #pragma unroll
        for (int kk = 0; kk < 2; ++kk)
            a[mt][kk] = wbase[(mt * 2 + kk) * 64 + lane];

    // ---- stage x -> LDS: lane owns (p = wv*2+pp, w-quad = lane&7, c-octet = lane>>3)
    {
        const int swq = lane & 7;          // w-quad (w = swq*4+i)
        const int sco = lane >> 3;         // c-octet (c = sco*8+cc)
        #pragma unroll
        for (int pp = 0; pp < 2; ++pp) {
            const int p = wv * 2 + pp;     // 0..7
            const float* xp = x + ((size_t)(b * 64 + sco * 8)) * 65536
                                + (size_t)(row0 + p) * 256 + w0 + swq * 4;
            f32x4 v[8];
            #pragma unroll
            for (int cc = 0; cc < 8; ++cc)
                v[cc] = *(const f32x4*)(xp + (size_t)cc * 65536);  // full 128-B lines
            #pragma unroll
            for (int i = 0; i < 4; ++i) {
                const int w = swq * 4 + i;
                bf16x8 e;
                #pragma unroll
                for (int cc = 0; cc < 8; ++cc)
                    e[cc] = (__bf16)v[cc][i];
                *(bf16x8*)(smem + p * 4096 + w * 128
                           + ((sco * 16) ^ ((w & 7) << 4) ^ ((p & 7) << 4))) = e;
            }
        }
    }
    __syncthreads();

    // ---- B fragments: one ds_read_b128 each ----
    bf16x8 bfrag[4][2];
    #pragma unroll
    for (int nt = 0; nt < 4; ++nt) {
        const int p = wrow * 4 + nt;       // 0..7
        const int w = pat * 16 + q;
        #pragma unroll
        for (int kk = 0; kk < 2; ++kk) {
            const int co = kk * 4 + hi;
            bfrag[nt][kk] = *(const bf16x8*)(smem + p * 4096 + w * 128
                            + ((co * 16) ^ ((w & 7) << 4) ^ ((p & 7) << 4)));
        }
    }
    __syncthreads();                       // x-LDS reusable for out-stage

    // ---- MFMA + out staging in two o-halves (o = h*32 + o2) ----
    const int u2t = t >> 3;                // 0..31
    const int wq2 = t & 7;
    #pragma unroll
    for (int h = 0; h < 2; ++h) {
        f32x4 acc[2][4];
        #pragma unroll
        for (int m2 = 0; m2 < 2; ++m2)
            #pragma unroll
            for (int nt = 0; nt < 4; ++nt)
                acc[m2][nt] = (f32x4){0.f, 0.f, 0.f, 0.f};

        #pragma unroll
        for (int m2 = 0; m2 < 2; ++m2) {
            const int mt = h * 2 + m2;
            #pragma unroll
            for (int nt = 0; nt < 4; ++nt) {
                acc[m2][nt] = __builtin_amdgcn_mfma_f32_16x16x32_bf16(
                    a[mt][0], bfrag[nt][0], acc[m2][nt], 0, 0, 0);
                acc[m2][nt] = __builtin_amdgcn_mfma_f32_16x16x32_bf16(
                    a[mt][1], bfrag[nt][1], acc[m2][nt], 0, 0, 0);
            }
        }

        // acc -> LDS: f32 idx (o2*8 + p)*32 + (w ^ ((o2&7)<<2)), 32 KiB
        #pragma unroll
        for (int m2 = 0; m2 < 2; ++m2)
            #pragma unroll
            for (int nt = 0; nt < 4; ++nt) {
                const int p = wrow * 4 + nt;
                #pragma unroll
                for (int r = 0; r < 4; ++r) {
                    const int o2 = m2 * 16 + hi * 4 + r;
                    const int w  = pat * 16 + q;
                    smemf[(o2 * 8 + p) * 32 + (w ^ ((o2 & 7) << 2))] = acc[m2][nt][r];
                }
            }
        __syncthreads();

        // wide f32x4 stores: 8 passes x 32 lines (full 128-B lines)
        #pragma unroll
        for (int ps = 0; ps < 8; ++ps) {
            const int r2 = ps * 32 + u2t;  // 0..255
            const int o2 = r2 >> 3;
            const int p  = r2 & 7;
            f32x4 vv = *(const f32x4*)&smemf[(o2 * 8 + p) * 32
                                             + ((wq2 * 4) ^ ((o2 & 7) << 2))];
            *(f32x4*)(out + ((size_t)(b * 64 + h * 32 + o2)) * 65536
                          + (size_t)(row0 + p) * 256 + w0 + wq2 * 4) = vv;
        }
        __syncthreads();
    }
}

// ---------------------------------------------------------------------------
// Fallback (round-2 single kernel, proven) if ws is too small.
// ---------------------------------------------------------------------------
__global__ __launch_bounds__(512) void hyperpatch_fallback(
    const float* __restrict__ x,
    const float* __restrict__ s,
    float* __restrict__ out)
{
    __shared__ bf16x8 afrag[2][512];
    const int bid = blockIdx.x;
    const int b   = bid >> 7;
    const int pi  = (bid >> 3) & 15;
    const int pj0 = (bid & 7) * 2;
    const int t   = threadIdx.x;
    const int lane = t & 63;
    const int wv   = t >> 6;

    {
        const int g  = t;
        const int mt = g >> 7;
        const int kk = (g >> 6) & 1;
        const int gl = g & 63;
        const int o  = mt * 16 + (gl & 15);
        const int c0 = kk * 32 + (gl >> 4) * 8;
        const float2* sb2 = reinterpret_cast<const float2*>(
            s + ((size_t)b * 4096) * 256 + pi * 16 + pj0);
        bf16x8 ta, tb;
        #pragma unroll
        for (int j = 0; j < 8; ++j) {
            float2 v = sb2[(size_t)(o * 64 + c0 + j) * 128];
            ta[j] = (__bf16)v.x;
            tb[j] = (__bf16)v.y;
        }
        afrag[0][g] = ta;
        afrag[1][g] = tb;
    }

    const int pat  = wv >> 2;
    const int wrow = wv & 3;
    const int q  = lane & 15;
    const int cb = (lane >> 4) * 8;
    const float* xbase = x + (((size_t)b * 64) * 256 + pi * 16) * 256
                           + (pj0 + pat) * 16 + q;
    bf16x8 bfrag[4][2];
    #pragma unroll
    for (int nt = 0; nt < 4; ++nt) {
        const int p = wrow * 4 + nt;
        #pragma unroll
        for (int kk = 0; kk < 2; ++kk) {
            const int c = kk * 32 + cb;
            bf16x8 tv;
            #pragma unroll
            for (int j = 0; j < 8; ++j) {
                float v = xbase[(size_t)(c + j) * 65536 + (size_t)p * 256];
                tv[j] = (__bf16)v;
            }
            bfrag[nt][kk] = tv;
        }
    }

    __syncthreads();

    bf16x8 a[4][2];
    #pragma unroll
    for (int mt = 0; mt < 4; ++mt)
        #pragma unroll
        for (int kk = 0; kk < 2; ++kk)
            a[mt][kk] = afrag[pat][(mt * 2 + kk) * 64 + lane];

    f32x4 acc[4][4];
    #pragma unroll
    for (int mt = 0; mt < 4; ++mt)
        #pragma unroll
        for (int nt = 0; nt < 4; ++nt)
            acc[mt][nt] = (f32x4){0.f, 0.f, 0.f, 0.f};

    #pragma unroll
    for (int mt = 0; mt < 4; ++mt) {
        #pragma unroll
        for (int nt = 0; nt < 4; ++nt) {
            acc[mt][nt] = __builtin_amdgcn_mfma_f32_16x16x32_bf16(
                a[mt][0], bfrag[nt][0], acc[mt][nt], 0, 0, 0);
            acc[mt][nt] = __builtin_amdgcn_mfma_f32_16x16x32_bf16(
                a[mt][1], bfrag[nt][1], acc[mt][nt], 0, 0, 0);
        }
    }

    const int ro = (lane >> 4) * 4;
    float* obase = out + (((size_t)b * 64) * 256 + pi * 16) * 256
                       + (pj0 + pat) * 16 + q;
    #pragma unroll
    for (int mt = 0; mt < 4; ++mt) {
        #pragma unroll
        for (int nt = 0; nt < 4; ++nt) {
            const int p = wrow * 4 + nt;
            #pragma unroll
            for (int r = 0; r < 4; ++r) {
                const int o = mt * 16 + ro + r;
                obase[(size_t)o * 65536 + (size_t)p * 256] = acc[mt][nt][r];
            }
        }
    }
}

extern "C" void kernel_launch(void* const* d_in, const int* in_sizes, int n_in,
                              void* d_out, int out_size, void* d_ws, size_t ws_size,
                              hipStream_t stream)
{
    (void)in_sizes; (void)n_in; (void)out_size;
    const float* x = (const float*)d_in[0];
    const float* s = (const float*)d_in[1];
    float* out = (float*)d_out;

    if (ws_size >= WS_BYTES && d_ws != nullptr) {
        bf16x8* ws = (bf16x8*)d_ws;
        pack_w_kernel<<<dim3(1024), dim3(256), 0, stream>>>(s, ws);
        gemm_kernel<<<dim3(2048), dim3(256), 0, stream>>>(x, ws, out);
    } else {
        hyperpatch_fallback<<<dim3(NB * FH * (FW / 2)), dim3(512), 0, stream>>>(x, s, out);
    }
}